// Round 1
// baseline (814.844 us; speedup 1.0000x reference)
//
#include <hip/hip_runtime.h>

#define N_NODES 100000
#define N_EDGES 1600000
#define TOTE    (N_EDGES + N_NODES)
#define NEG     0.2f

// ====================== CSR build ======================
__global__ __launch_bounds__(256) void k_init_counts(int* __restrict__ counts) {
  int i = blockIdx.x * 256 + threadIdx.x;
  if (i < N_NODES) counts[i] = 1;  // self loop
}

__global__ __launch_bounds__(256) void k_hist(const int* __restrict__ ei, int* __restrict__ counts) {
  int e = blockIdx.x * 256 + threadIdx.x;
  if (e < N_EDGES) atomicAdd(&counts[ei[N_EDGES + e]], 1);
}

__global__ __launch_bounds__(256) void k_scan_sums(const int* __restrict__ counts, int* __restrict__ bsums) {
  __shared__ int red[256];
  int t = threadIdx.x;
  int idx0 = blockIdx.x * 1024 + t * 4;
  int s = 0;
#pragma unroll
  for (int i = 0; i < 4; ++i) { int idx = idx0 + i; if (idx < N_NODES) s += counts[idx]; }
  red[t] = s; __syncthreads();
#pragma unroll
  for (int off = 128; off > 0; off >>= 1) { if (t < off) red[t] += red[t + off]; __syncthreads(); }
  if (t == 0) bsums[blockIdx.x] = red[0];
}

__global__ void k_scan_tops(int* __restrict__ bsums, int nb) {
  if (threadIdx.x == 0 && blockIdx.x == 0) {
    int run = 0;
    for (int i = 0; i < nb; ++i) { int v = bsums[i]; bsums[i] = run; run += v; }
  }
}

__global__ __launch_bounds__(256) void k_scan_chunks(const int* __restrict__ counts,
                                                     const int* __restrict__ bsums,
                                                     int* __restrict__ offs, int* __restrict__ cursor) {
  __shared__ int sc[256];
  int t = threadIdx.x;
  int idx0 = blockIdx.x * 1024 + t * 4;
  int v[4]; int local = 0;
#pragma unroll
  for (int i = 0; i < 4; ++i) { int idx = idx0 + i; v[i] = (idx < N_NODES) ? counts[idx] : 0; local += v[i]; }
  sc[t] = local; __syncthreads();
  for (int off = 1; off < 256; off <<= 1) {
    int x = (t >= off) ? sc[t - off] : 0;
    __syncthreads();
    sc[t] += x;
    __syncthreads();
  }
  int run = sc[t] - local + bsums[blockIdx.x];
#pragma unroll
  for (int i = 0; i < 4; ++i) {
    int idx = idx0 + i;
    if (idx < N_NODES) { offs[idx] = run; cursor[idx] = run; run += v[i]; }
  }
}

__global__ __launch_bounds__(256) void k_scatter(const int* __restrict__ ei, int* __restrict__ cursor,
                                                 int* __restrict__ srcs, int* __restrict__ offs) {
  int idx = blockIdx.x * 256 + threadIdx.x;
  if (idx == 0) offs[N_NODES] = TOTE;
  if (idx < TOTE) {
    int s, d;
    if (idx < N_EDGES) { s = ei[idx]; d = ei[N_EDGES + idx]; }
    else { s = idx - N_EDGES; d = s; }
    int pos = atomicAdd(&cursor[d], 1);
    srcs[pos] = s;
  }
}

// ====================== GEMM [M,128] @ [128,128] (fp32 vector ALU) ======================
__global__ __launch_bounds__(256) void k_gemm(const float* __restrict__ A, const float* __restrict__ W,
                                              float* __restrict__ C) {
  __shared__ float sA[128][36];   // 128 rows x 32 k (+4 pad, keeps float4 alignment)
  __shared__ float sB[32][128];
  int t = threadIdx.x;
  int row0 = blockIdx.x * 128;
  int tx = t & 15;        // cols tx*8
  int ty = t >> 4;        // rows ty*8
  float acc[8][8];
#pragma unroll
  for (int i = 0; i < 8; ++i)
#pragma unroll
    for (int j = 0; j < 8; ++j) acc[i][j] = 0.f;

  for (int k0 = 0; k0 < 128; k0 += 32) {
#pragma unroll
    for (int i = 0; i < 4; ++i) {
      int f = t + i * 256;         // 0..1023 float4 tiles of A chunk
      int r = f >> 3, c4 = f & 7;
      float4 v = make_float4(0.f, 0.f, 0.f, 0.f);
      int gr = row0 + r;
      if (gr < N_NODES) v = *reinterpret_cast<const float4*>(A + (size_t)gr * 128 + k0 + c4 * 4);
      *reinterpret_cast<float4*>(&sA[r][c4 * 4]) = v;
    }
#pragma unroll
    for (int i = 0; i < 4; ++i) {
      int f = t + i * 256;
      int r = f >> 5, c4 = f & 31;
      *reinterpret_cast<float4*>(&sB[r][c4 * 4]) =
          *reinterpret_cast<const float4*>(W + (size_t)(k0 + r) * 128 + c4 * 4);
    }
    __syncthreads();
#pragma unroll
    for (int k = 0; k < 32; ++k) {
      float a[8], b[8];
#pragma unroll
      for (int i = 0; i < 8; ++i) a[i] = sA[ty * 8 + i][k];
      float4 b0 = *reinterpret_cast<const float4*>(&sB[k][tx * 8]);
      float4 b1 = *reinterpret_cast<const float4*>(&sB[k][tx * 8 + 4]);
      b[0] = b0.x; b[1] = b0.y; b[2] = b0.z; b[3] = b0.w;
      b[4] = b1.x; b[5] = b1.y; b[6] = b1.z; b[7] = b1.w;
#pragma unroll
      for (int i = 0; i < 8; ++i)
#pragma unroll
        for (int j = 0; j < 8; ++j) acc[i][j] += a[i] * b[j];
    }
    __syncthreads();
  }
#pragma unroll
  for (int i = 0; i < 8; ++i) {
    int gr = row0 + ty * 8 + i;
    if (gr < N_NODES) {
      float4 o0 = make_float4(acc[i][0], acc[i][1], acc[i][2], acc[i][3]);
      float4 o1 = make_float4(acc[i][4], acc[i][5], acc[i][6], acc[i][7]);
      *reinterpret_cast<float4*>(C + (size_t)gr * 128 + tx * 8) = o0;
      *reinterpret_cast<float4*>(C + (size_t)gr * 128 + tx * 8 + 4) = o1;
    }
  }
}

// ====================== per-node attention scalars ======================
__global__ __launch_bounds__(256) void k_alphas(const float* __restrict__ h, const float* __restrict__ avS,
                                                const float* __restrict__ avD,
                                                float* __restrict__ outS, float* __restrict__ outD) {
  int gw = (blockIdx.x * 256 + threadIdx.x) >> 6;
  int lane = threadIdx.x & 63;
  if (gw >= N_NODES) return;
  float2 hv = *reinterpret_cast<const float2*>(h + (size_t)gw * 128 + lane * 2);
  float2 sv = *reinterpret_cast<const float2*>(avS + lane * 2);
  float2 dv = *reinterpret_cast<const float2*>(avD + lane * 2);
  float ps = hv.x * sv.x + hv.y * sv.y;
  float pd = hv.x * dv.x + hv.y * dv.y;
#pragma unroll
  for (int off = 32; off > 0; off >>= 1) {
    ps += __shfl_xor(ps, off);
    pd += __shfl_xor(pd, off);
  }
  if (lane == 0) { outS[gw] = ps; outD[gw] = pd; }
}

// ====================== softmax + weighted aggregation (wave per dst node) ======================
__global__ __launch_bounds__(256) void k_aggregate(const float* __restrict__ h, const float* __restrict__ aS,
                                                   const float* __restrict__ aD, const int* __restrict__ offs,
                                                   const int* __restrict__ srcs, const float* __restrict__ bias,
                                                   float* __restrict__ out, int relu) {
  int gw = (blockIdx.x * 256 + threadIdx.x) >> 6;
  int lane = threadIdx.x & 63;
  if (gw >= N_NODES) return;
  int beg = offs[gw], end = offs[gw + 1];
  float adn = aD[gw];

  // pass 1: segment max (stable softmax)
  float m = -1e30f;
  for (int i = beg + lane; i < end; i += 64) {
    float e = aS[srcs[i]] + adn;
    e = (e > 0.f) ? e : NEG * e;
    m = fmaxf(m, e);
  }
#pragma unroll
  for (int off = 32; off > 0; off >>= 1) m = fmaxf(m, __shfl_xor(m, off));

  // pass 2: exp, denom, weighted feature sum
  float denom = 0.f, acc0 = 0.f, acc1 = 0.f;
  for (int base = beg; base < end; base += 64) {
    int i = base + lane;
    float ex = 0.f; int s = 0;
    if (i < end) {
      s = srcs[i];
      float e = aS[s] + adn;
      e = (e > 0.f) ? e : NEG * e;
      ex = __expf(e - m);
    }
    denom += ex;
    int cnt = min(64, end - base);
    for (int j = 0; j < cnt; ++j) {
      float exj = __shfl(ex, j);
      int sj = __shfl(s, j);
      float2 hv = *reinterpret_cast<const float2*>(h + (size_t)sj * 128 + lane * 2);
      acc0 += exj * hv.x;
      acc1 += exj * hv.y;
    }
  }
#pragma unroll
  for (int off = 32; off > 0; off >>= 1) denom += __shfl_xor(denom, off);
  float inv = 1.f / (denom + 1e-16f);
  float2 bv = *reinterpret_cast<const float2*>(bias + lane * 2);
  float o0 = acc0 * inv + bv.x;
  float o1 = acc1 * inv + bv.y;
  if (relu) { o0 = fmaxf(o0, 0.f); o1 = fmaxf(o1, 0.f); }
  *reinterpret_cast<float2*>(out + (size_t)gw * 128 + lane * 2) = make_float2(o0, o1);
}

// ====================== final classifier [N,128]@[128,10]+b ======================
__global__ __launch_bounds__(256) void k_linear(const float* __restrict__ h, const float* __restrict__ Wl,
                                                const float* __restrict__ bl, float* __restrict__ out) {
  __shared__ float sW[128 * 10];
  __shared__ float sb[10];
  int t = threadIdx.x;
  for (int i = t; i < 1280; i += 256) sW[i] = Wl[i];
  if (t < 10) sb[t] = bl[t];
  __syncthreads();
  int gw = (blockIdx.x * 256 + t) >> 6;
  int lane = t & 63;
  if (gw >= N_NODES) return;
  float2 hv = *reinterpret_cast<const float2*>(h + (size_t)gw * 128 + lane * 2);
  float p[10];
#pragma unroll
  for (int c = 0; c < 10; ++c)
    p[c] = hv.x * sW[(2 * lane) * 10 + c] + hv.y * sW[(2 * lane + 1) * 10 + c];
#pragma unroll
  for (int off = 32; off > 0; off >>= 1)
#pragma unroll
    for (int c = 0; c < 10; ++c) p[c] += __shfl_xor(p[c], off);
  if (lane == 0) {
#pragma unroll
    for (int c = 0; c < 10; ++c) out[(size_t)gw * 10 + c] = p[c] + sb[c];
  }
}

// ====================== launch ======================
extern "C" void kernel_launch(void* const* d_in, const int* in_sizes, int n_in,
                              void* d_out, int out_size, void* d_ws, size_t ws_size,
                              hipStream_t stream) {
  const float* x   = (const float*)d_in[0];
  const int*   ei  = (const int*)d_in[1];
  // d_in[2] = batch (unused)
  const float* W1  = (const float*)d_in[3];
  const float* as1 = (const float*)d_in[4];
  const float* ad1 = (const float*)d_in[5];
  const float* b1  = (const float*)d_in[6];
  const float* W2  = (const float*)d_in[7];
  const float* as2 = (const float*)d_in[8];
  const float* ad2 = (const float*)d_in[9];
  const float* b2  = (const float*)d_in[10];
  const float* Wl  = (const float*)d_in[11];
  const float* bl  = (const float*)d_in[12];
  float* out = (float*)d_out;

  char* p = (char*)d_ws;
  float* bufA  = (float*)p; p += (size_t)N_NODES * 128 * sizeof(float);
  float* bufB  = (float*)p; p += (size_t)N_NODES * 128 * sizeof(float);
  float* aS    = (float*)p; p += (size_t)N_NODES * sizeof(float);
  float* aD    = (float*)p; p += (size_t)N_NODES * sizeof(float);
  int* counts  = (int*)p;   p += (size_t)N_NODES * sizeof(int);
  int* offs    = (int*)p;   p += (size_t)(N_NODES + 4) * sizeof(int);
  int* cursor  = (int*)p;   p += (size_t)N_NODES * sizeof(int);
  int* bsums   = (int*)p;   p += 1024 * sizeof(int);
  int* srcs    = (int*)p;   p += (size_t)TOTE * sizeof(int);

  int nbScan = (N_NODES + 1023) / 1024;

  k_init_counts<<<(N_NODES + 255) / 256, 256, 0, stream>>>(counts);
  k_hist<<<(N_EDGES + 255) / 256, 256, 0, stream>>>(ei, counts);
  k_scan_sums<<<nbScan, 256, 0, stream>>>(counts, bsums);
  k_scan_tops<<<1, 64, 0, stream>>>(bsums, nbScan);
  k_scan_chunks<<<nbScan, 256, 0, stream>>>(counts, bsums, offs, cursor);
  k_scatter<<<(TOTE + 255) / 256, 256, 0, stream>>>(ei, cursor, srcs, offs);

  int gemmBlocks = (N_NODES + 127) / 128;
  int waveBlocks = (N_NODES + 3) / 4;

  // layer 1
  k_gemm<<<gemmBlocks, 256, 0, stream>>>(x, W1, bufA);
  k_alphas<<<waveBlocks, 256, 0, stream>>>(bufA, as1, ad1, aS, aD);
  k_aggregate<<<waveBlocks, 256, 0, stream>>>(bufA, aS, aD, offs, srcs, b1, bufB, 1);
  // layer 2
  k_gemm<<<gemmBlocks, 256, 0, stream>>>(bufB, W2, bufA);
  k_alphas<<<waveBlocks, 256, 0, stream>>>(bufA, as2, ad2, aS, aD);
  k_aggregate<<<waveBlocks, 256, 0, stream>>>(bufA, aS, aD, offs, srcs, b2, bufB, 1);
  // classifier
  k_linear<<<waveBlocks, 256, 0, stream>>>(bufB, Wl, bl, out);
}

// Round 2
// 667.622 us; speedup vs baseline: 1.2205x; 1.2205x over previous
//
#include <hip/hip_runtime.h>

#define N_NODES 100000
#define N_EDGES 1600000
#define TOTE    (N_EDGES + N_NODES)
#define NEG     0.2f

// bf16 helpers (RTNE)
__device__ __forceinline__ unsigned short f2bf(float f) {
  unsigned int u = __float_as_uint(f);
  u += 0x7fffu + ((u >> 16) & 1u);
  return (unsigned short)(u >> 16);
}
__device__ __forceinline__ float bf_lo(unsigned int r) { return __uint_as_float(r << 16); }
__device__ __forceinline__ float bf_hi(unsigned int r) { return __uint_as_float(r & 0xffff0000u); }

// ====================== CSR build ======================
__global__ __launch_bounds__(256) void k_init_counts(int* __restrict__ counts) {
  int i = blockIdx.x * 256 + threadIdx.x;
  if (i < N_NODES) counts[i] = 1;  // self loop
}

__global__ __launch_bounds__(256) void k_hist(const int* __restrict__ ei, int* __restrict__ counts) {
  int e = blockIdx.x * 256 + threadIdx.x;
  if (e < N_EDGES) atomicAdd(&counts[ei[N_EDGES + e]], 1);
}

__global__ __launch_bounds__(256) void k_scan_sums(const int* __restrict__ counts, int* __restrict__ bsums) {
  __shared__ int red[256];
  int t = threadIdx.x;
  int idx0 = blockIdx.x * 1024 + t * 4;
  int s = 0;
#pragma unroll
  for (int i = 0; i < 4; ++i) { int idx = idx0 + i; if (idx < N_NODES) s += counts[idx]; }
  red[t] = s; __syncthreads();
#pragma unroll
  for (int off = 128; off > 0; off >>= 1) { if (t < off) red[t] += red[t + off]; __syncthreads(); }
  if (t == 0) bsums[blockIdx.x] = red[0];
}

__global__ void k_scan_tops(int* __restrict__ bsums, int nb) {
  if (threadIdx.x == 0 && blockIdx.x == 0) {
    int run = 0;
    for (int i = 0; i < nb; ++i) { int v = bsums[i]; bsums[i] = run; run += v; }
  }
}

__global__ __launch_bounds__(256) void k_scan_chunks(const int* __restrict__ counts,
                                                     const int* __restrict__ bsums,
                                                     int* __restrict__ offs, int* __restrict__ cursor) {
  __shared__ int sc[256];
  int t = threadIdx.x;
  int idx0 = blockIdx.x * 1024 + t * 4;
  int v[4]; int local = 0;
#pragma unroll
  for (int i = 0; i < 4; ++i) { int idx = idx0 + i; v[i] = (idx < N_NODES) ? counts[idx] : 0; local += v[i]; }
  sc[t] = local; __syncthreads();
  for (int off = 1; off < 256; off <<= 1) {
    int x = (t >= off) ? sc[t - off] : 0;
    __syncthreads();
    sc[t] += x;
    __syncthreads();
  }
  int run = sc[t] - local + bsums[blockIdx.x];
#pragma unroll
  for (int i = 0; i < 4; ++i) {
    int idx = idx0 + i;
    if (idx < N_NODES) { offs[idx] = run; cursor[idx] = run; run += v[i]; }
  }
}

__global__ __launch_bounds__(256) void k_scatter(const int* __restrict__ ei, int* __restrict__ cursor,
                                                 int* __restrict__ srcs, int* __restrict__ offs) {
  int idx = blockIdx.x * 256 + threadIdx.x;
  if (idx == 0) offs[N_NODES] = TOTE;
  if (idx < TOTE) {
    int s, d;
    if (idx < N_EDGES) { s = ei[idx]; d = ei[N_EDGES + idx]; }
    else { s = idx - N_EDGES; d = s; }
    int pos = atomicAdd(&cursor[d], 1);
    srcs[pos] = s;
  }
}

// ====================== GEMM [M,128] @ [128,128] (fp32 vector ALU, bf16 out) ======================
__global__ __launch_bounds__(256) void k_gemm(const float* __restrict__ A, const float* __restrict__ W,
                                              unsigned short* __restrict__ Cb) {
  __shared__ float sA[128][36];   // 128 rows x 32 k (+4 pad, keeps float4 alignment)
  __shared__ float sB[32][128];
  int t = threadIdx.x;
  int row0 = blockIdx.x * 128;
  int tx = t & 15;        // cols tx*8
  int ty = t >> 4;        // rows ty*8
  float acc[8][8];
#pragma unroll
  for (int i = 0; i < 8; ++i)
#pragma unroll
    for (int j = 0; j < 8; ++j) acc[i][j] = 0.f;

  for (int k0 = 0; k0 < 128; k0 += 32) {
#pragma unroll
    for (int i = 0; i < 4; ++i) {
      int f = t + i * 256;
      int r = f >> 3, c4 = f & 7;
      float4 v = make_float4(0.f, 0.f, 0.f, 0.f);
      int gr = row0 + r;
      if (gr < N_NODES) v = *reinterpret_cast<const float4*>(A + (size_t)gr * 128 + k0 + c4 * 4);
      *reinterpret_cast<float4*>(&sA[r][c4 * 4]) = v;
    }
#pragma unroll
    for (int i = 0; i < 4; ++i) {
      int f = t + i * 256;
      int r = f >> 5, c4 = f & 31;
      *reinterpret_cast<float4*>(&sB[r][c4 * 4]) =
          *reinterpret_cast<const float4*>(W + (size_t)(k0 + r) * 128 + c4 * 4);
    }
    __syncthreads();
#pragma unroll
    for (int k = 0; k < 32; ++k) {
      float a[8], b[8];
#pragma unroll
      for (int i = 0; i < 8; ++i) a[i] = sA[ty * 8 + i][k];
      float4 b0 = *reinterpret_cast<const float4*>(&sB[k][tx * 8]);
      float4 b1 = *reinterpret_cast<const float4*>(&sB[k][tx * 8 + 4]);
      b[0] = b0.x; b[1] = b0.y; b[2] = b0.z; b[3] = b0.w;
      b[4] = b1.x; b[5] = b1.y; b[6] = b1.z; b[7] = b1.w;
#pragma unroll
      for (int i = 0; i < 8; ++i)
#pragma unroll
        for (int j = 0; j < 8; ++j) acc[i][j] += a[i] * b[j];
    }
    __syncthreads();
  }
#pragma unroll
  for (int i = 0; i < 8; ++i) {
    int gr = row0 + ty * 8 + i;
    if (gr < N_NODES) {
      union { ushort4 s4[2]; uint4 u4; } o;
#pragma unroll
      for (int j = 0; j < 8; ++j) ((unsigned short*)&o)[j] = f2bf(acc[i][j]);
      *reinterpret_cast<uint4*>(Cb + (size_t)gr * 128 + tx * 8) = o.u4;
    }
  }
}

// ====================== per-node attention scalars (bf16 h) ======================
__global__ __launch_bounds__(256) void k_alphas(const unsigned short* __restrict__ hb,
                                                const float* __restrict__ avS,
                                                const float* __restrict__ avD,
                                                float* __restrict__ outS, float* __restrict__ outD) {
  int gw = (blockIdx.x * 256 + threadIdx.x) >> 6;
  int lane = threadIdx.x & 63;
  if (gw >= N_NODES) return;
  unsigned int r = *reinterpret_cast<const unsigned int*>(hb + (size_t)gw * 128 + lane * 2);
  float hx = bf_lo(r), hy = bf_hi(r);
  float2 sv = *reinterpret_cast<const float2*>(avS + lane * 2);
  float2 dv = *reinterpret_cast<const float2*>(avD + lane * 2);
  float ps = hx * sv.x + hy * sv.y;
  float pd = hx * dv.x + hy * dv.y;
#pragma unroll
  for (int off = 32; off > 0; off >>= 1) {
    ps += __shfl_xor(ps, off);
    pd += __shfl_xor(pd, off);
  }
  if (lane == 0) { outS[gw] = ps; outD[gw] = pd; }
}

// ====================== softmax + weighted aggregation (wave per dst node, bf16 gather) ==========
__global__ __launch_bounds__(256) void k_aggregate(const unsigned short* __restrict__ hb,
                                                   const float* __restrict__ aS,
                                                   const float* __restrict__ aD, const int* __restrict__ offs,
                                                   const int* __restrict__ srcs, const float* __restrict__ bias,
                                                   float* __restrict__ out, int relu) {
  int gw = (blockIdx.x * 256 + threadIdx.x) >> 6;
  int lane = threadIdx.x & 63;
  if (gw >= N_NODES) return;
  int beg = offs[gw], end = offs[gw + 1];
  float adn = aD[gw];

  // pass 1: segment max (stable softmax)
  float m = -1e30f;
  for (int i = beg + lane; i < end; i += 64) {
    float e = aS[srcs[i]] + adn;
    e = (e > 0.f) ? e : NEG * e;
    m = fmaxf(m, e);
  }
#pragma unroll
  for (int off = 32; off > 0; off >>= 1) m = fmaxf(m, __shfl_xor(m, off));

  // pass 2: exp, denom, weighted feature sum (8-deep pipelined row gather)
  float denom = 0.f, acc0 = 0.f, acc1 = 0.f;
  const unsigned int laneOff = lane * 2;
  for (int base = beg; base < end; base += 64) {
    int i = base + lane;
    float ex = 0.f; int s = 0;
    if (i < end) {
      s = srcs[i];
      float e = aS[s] + adn;
      e = (e > 0.f) ? e : NEG * e;
      ex = __expf(e - m);
    }
    denom += ex;
    int cnt = min(64, end - base);
    int j = 0;
    for (; j + 8 <= cnt; j += 8) {
      float e0 = __shfl(ex, j + 0), e1 = __shfl(ex, j + 1), e2 = __shfl(ex, j + 2), e3 = __shfl(ex, j + 3);
      float e4 = __shfl(ex, j + 4), e5 = __shfl(ex, j + 5), e6 = __shfl(ex, j + 6), e7 = __shfl(ex, j + 7);
      int s0 = __shfl(s, j + 0), s1 = __shfl(s, j + 1), s2 = __shfl(s, j + 2), s3 = __shfl(s, j + 3);
      int s4 = __shfl(s, j + 4), s5 = __shfl(s, j + 5), s6 = __shfl(s, j + 6), s7 = __shfl(s, j + 7);
      unsigned int r0 = *reinterpret_cast<const unsigned int*>(hb + (size_t)s0 * 128 + laneOff);
      unsigned int r1 = *reinterpret_cast<const unsigned int*>(hb + (size_t)s1 * 128 + laneOff);
      unsigned int r2 = *reinterpret_cast<const unsigned int*>(hb + (size_t)s2 * 128 + laneOff);
      unsigned int r3 = *reinterpret_cast<const unsigned int*>(hb + (size_t)s3 * 128 + laneOff);
      unsigned int r4 = *reinterpret_cast<const unsigned int*>(hb + (size_t)s4 * 128 + laneOff);
      unsigned int r5 = *reinterpret_cast<const unsigned int*>(hb + (size_t)s5 * 128 + laneOff);
      unsigned int r6 = *reinterpret_cast<const unsigned int*>(hb + (size_t)s6 * 128 + laneOff);
      unsigned int r7 = *reinterpret_cast<const unsigned int*>(hb + (size_t)s7 * 128 + laneOff);
      acc0 += e0 * bf_lo(r0); acc1 += e0 * bf_hi(r0);
      acc0 += e1 * bf_lo(r1); acc1 += e1 * bf_hi(r1);
      acc0 += e2 * bf_lo(r2); acc1 += e2 * bf_hi(r2);
      acc0 += e3 * bf_lo(r3); acc1 += e3 * bf_hi(r3);
      acc0 += e4 * bf_lo(r4); acc1 += e4 * bf_hi(r4);
      acc0 += e5 * bf_lo(r5); acc1 += e5 * bf_hi(r5);
      acc0 += e6 * bf_lo(r6); acc1 += e6 * bf_hi(r6);
      acc0 += e7 * bf_lo(r7); acc1 += e7 * bf_hi(r7);
    }
    for (; j < cnt; ++j) {
      float exj = __shfl(ex, j);
      int sj = __shfl(s, j);
      unsigned int r = *reinterpret_cast<const unsigned int*>(hb + (size_t)sj * 128 + laneOff);
      acc0 += exj * bf_lo(r);
      acc1 += exj * bf_hi(r);
    }
  }
#pragma unroll
  for (int off = 32; off > 0; off >>= 1) denom += __shfl_xor(denom, off);
  float inv = 1.f / (denom + 1e-16f);
  float2 bv = *reinterpret_cast<const float2*>(bias + lane * 2);
  float o0 = acc0 * inv + bv.x;
  float o1 = acc1 * inv + bv.y;
  if (relu) { o0 = fmaxf(o0, 0.f); o1 = fmaxf(o1, 0.f); }
  *reinterpret_cast<float2*>(out + (size_t)gw * 128 + lane * 2) = make_float2(o0, o1);
}

// ====================== final classifier [N,128]@[128,10]+b ======================
__global__ __launch_bounds__(256) void k_linear(const float* __restrict__ h, const float* __restrict__ Wl,
                                                const float* __restrict__ bl, float* __restrict__ out) {
  __shared__ float sW[128 * 10];
  __shared__ float sb[10];
  int t = threadIdx.x;
  for (int i = t; i < 1280; i += 256) sW[i] = Wl[i];
  if (t < 10) sb[t] = bl[t];
  __syncthreads();
  int gw = (blockIdx.x * 256 + t) >> 6;
  int lane = t & 63;
  if (gw >= N_NODES) return;
  float2 hv = *reinterpret_cast<const float2*>(h + (size_t)gw * 128 + lane * 2);
  float p[10];
#pragma unroll
  for (int c = 0; c < 10; ++c)
    p[c] = hv.x * sW[(2 * lane) * 10 + c] + hv.y * sW[(2 * lane + 1) * 10 + c];
#pragma unroll
  for (int off = 32; off > 0; off >>= 1)
#pragma unroll
    for (int c = 0; c < 10; ++c) p[c] += __shfl_xor(p[c], off);
  if (lane == 0) {
#pragma unroll
    for (int c = 0; c < 10; ++c) out[(size_t)gw * 10 + c] = p[c] + sb[c];
  }
}

// ====================== launch ======================
extern "C" void kernel_launch(void* const* d_in, const int* in_sizes, int n_in,
                              void* d_out, int out_size, void* d_ws, size_t ws_size,
                              hipStream_t stream) {
  const float* x   = (const float*)d_in[0];
  const int*   ei  = (const int*)d_in[1];
  // d_in[2] = batch (unused)
  const float* W1  = (const float*)d_in[3];
  const float* as1 = (const float*)d_in[4];
  const float* ad1 = (const float*)d_in[5];
  const float* b1  = (const float*)d_in[6];
  const float* W2  = (const float*)d_in[7];
  const float* as2 = (const float*)d_in[8];
  const float* ad2 = (const float*)d_in[9];
  const float* b2  = (const float*)d_in[10];
  const float* Wl  = (const float*)d_in[11];
  const float* bl  = (const float*)d_in[12];
  float* out = (float*)d_out;

  char* p = (char*)d_ws;
  unsigned short* hb = (unsigned short*)p; p += (size_t)N_NODES * 128 * sizeof(unsigned short);
  float* bufB  = (float*)p; p += (size_t)N_NODES * 128 * sizeof(float);
  float* aS    = (float*)p; p += (size_t)N_NODES * sizeof(float);
  float* aD    = (float*)p; p += (size_t)N_NODES * sizeof(float);
  int* counts  = (int*)p;   p += (size_t)N_NODES * sizeof(int);
  int* offs    = (int*)p;   p += (size_t)(N_NODES + 4) * sizeof(int);
  int* cursor  = (int*)p;   p += (size_t)N_NODES * sizeof(int);
  int* bsums   = (int*)p;   p += 1024 * sizeof(int);
  int* srcs    = (int*)p;   p += (size_t)TOTE * sizeof(int);

  int nbScan = (N_NODES + 1023) / 1024;

  k_init_counts<<<(N_NODES + 255) / 256, 256, 0, stream>>>(counts);
  k_hist<<<(N_EDGES + 255) / 256, 256, 0, stream>>>(ei, counts);
  k_scan_sums<<<nbScan, 256, 0, stream>>>(counts, bsums);
  k_scan_tops<<<1, 64, 0, stream>>>(bsums, nbScan);
  k_scan_chunks<<<nbScan, 256, 0, stream>>>(counts, bsums, offs, cursor);
  k_scatter<<<(TOTE + 255) / 256, 256, 0, stream>>>(ei, cursor, srcs, offs);

  int gemmBlocks = (N_NODES + 127) / 128;
  int waveBlocks = (N_NODES + 3) / 4;

  // layer 1
  k_gemm<<<gemmBlocks, 256, 0, stream>>>(x, W1, hb);
  k_alphas<<<waveBlocks, 256, 0, stream>>>(hb, as1, ad1, aS, aD);
  k_aggregate<<<waveBlocks, 256, 0, stream>>>(hb, aS, aD, offs, srcs, b1, bufB, 1);
  // layer 2
  k_gemm<<<gemmBlocks, 256, 0, stream>>>(bufB, W2, hb);
  k_alphas<<<waveBlocks, 256, 0, stream>>>(hb, as2, ad2, aS, aD);
  k_aggregate<<<waveBlocks, 256, 0, stream>>>(hb, aS, aD, offs, srcs, b2, bufB, 1);
  // classifier
  k_linear<<<waveBlocks, 256, 0, stream>>>(bufB, Wl, bl, out);
}

// Round 3
// 525.151 us; speedup vs baseline: 1.5516x; 1.2713x over previous
//
#include <hip/hip_runtime.h>

#define N_NODES 100000
#define N_EDGES 1600000
#define TOTE    (N_EDGES + N_NODES)
#define NEG     0.2f
#define NB      ((N_NODES + 255) >> 8)   // 391 buckets of 256 nodes

// bf16 helpers (RTNE)
__device__ __forceinline__ unsigned short f2bf(float f) {
  unsigned int u = __float_as_uint(f);
  u += 0x7fffu + ((u >> 16) & 1u);
  return (unsigned short)(u >> 16);
}
__device__ __forceinline__ float bf_lo(unsigned int r) { return __uint_as_float(r << 16); }
__device__ __forceinline__ float bf_hi(unsigned int r) { return __uint_as_float(r & 0xffff0000u); }

// ====================== binned CSR build ======================
__global__ __launch_bounds__(256) void k_zero_bcnt(int* __restrict__ bucketCnt) {
  for (int i = threadIdx.x; i < NB * 16; i += 256) bucketCnt[i] = 0;
}

// bucket histogram over dst (LDS-staged; padded global counters, stride 16)
__global__ __launch_bounds__(256) void k_bucket_hist(const int* __restrict__ ei, int* __restrict__ bucketCnt) {
  __shared__ int h[NB];
  int t = threadIdx.x;
  for (int b = t; b < NB; b += 256) h[b] = 0;
  __syncthreads();
#pragma unroll
  for (int j = 0; j < 16; ++j) {
    int idx = blockIdx.x * 4096 + j * 256 + t;
    if (idx < N_EDGES) atomicAdd(&h[ei[N_EDGES + idx] >> 8], 1);
  }
  __syncthreads();
  for (int b = t; b < NB; b += 256) { int v = h[b]; if (v) atomicAdd(&bucketCnt[b * 16], v); }
}

// exclusive scan over 391 buckets (single block)
__global__ __launch_bounds__(512) void k_bin_scan(const int* __restrict__ bucketCnt,
                                                  int* __restrict__ binOffs, int* __restrict__ binCursor) {
  __shared__ int sc[512];
  int t = threadIdx.x;
  int v = (t < NB) ? bucketCnt[t * 16] : 0;
  sc[t] = v; __syncthreads();
  for (int off = 1; off < 512; off <<= 1) {
    int x = (t >= off) ? sc[t - off] : 0;
    __syncthreads();
    sc[t] += x;
    __syncthreads();
  }
  int excl = sc[t] - v;
  if (t <= NB) binOffs[t] = excl;
  if (t < NB) binCursor[t * 16] = excl;
}

// pass A: partition edges into bucket-major order, packed (src<<8)|(dst&255)
__global__ __launch_bounds__(256) void k_binA(const int* __restrict__ ei, int* __restrict__ binCursor,
                                              unsigned int* __restrict__ binned) {
  __shared__ int hist[NB];
  __shared__ int cur[NB];
  int t = threadIdx.x;
  for (int b = t; b < NB; b += 256) hist[b] = 0;
  __syncthreads();
  unsigned int pk[16]; int bk[16];
#pragma unroll
  for (int j = 0; j < 16; ++j) {
    int idx = blockIdx.x * 4096 + j * 256 + t;
    if (idx < N_EDGES) {
      int s = ei[idx], d = ei[N_EDGES + idx];
      bk[j] = d >> 8;
      pk[j] = ((unsigned int)s << 8) | (unsigned int)(d & 255);
      atomicAdd(&hist[bk[j]], 1);
    } else bk[j] = -1;
  }
  __syncthreads();
  for (int b = t; b < NB; b += 256) {
    int h = hist[b];
    if (h) cur[b] = atomicAdd(&binCursor[b * 16], h);
  }
  __syncthreads();
#pragma unroll
  for (int j = 0; j < 16; ++j) {
    if (bk[j] >= 0) {
      int pos = atomicAdd(&cur[bk[j]], 1);
      binned[pos] = pk[j];
    }
  }
}

// pass B: per-bucket exact CSR (offs + srcs), writes confined to one L2
__global__ __launch_bounds__(256) void k_binB(const unsigned int* __restrict__ binned,
                                              const int* __restrict__ binOffs,
                                              int* __restrict__ offs, int* __restrict__ srcs) {
  __shared__ int cnt[256];
  __shared__ int sc[256];
  __shared__ int cur[256];
  int b = blockIdx.x;
  int t = threadIdx.x;
  int node0 = b << 8;
  int nNodes = min(256, N_NODES - node0);
  int e0 = binOffs[b], e1 = binOffs[b + 1];
  int base = e0 + node0;  // prior real edges + prior self-loops

  cnt[t] = 0; __syncthreads();
  for (int i = e0 + t; i < e1; i += 256) atomicAdd(&cnt[binned[i] & 255u], 1);
  __syncthreads();

  int v = (t < nNodes) ? cnt[t] + 1 : 0;  // +1 self-loop
  sc[t] = v; __syncthreads();
  for (int off = 1; off < 256; off <<= 1) {
    int x = (t >= off) ? sc[t - off] : 0;
    __syncthreads();
    sc[t] += x;
    __syncthreads();
  }
  int excl = sc[t] - v;
  if (t < nNodes) {
    offs[node0 + t] = base + excl;
    srcs[base + excl] = node0 + t;  // self-loop first
  }
  cur[t] = excl + 1;
  __syncthreads();

  for (int i = e0 + t; i < e1; i += 256) {
    unsigned int e = binned[i];
    int j = (int)(e & 255u);
    int s = (int)(e >> 8);
    int p = atomicAdd(&cur[j], 1);
    srcs[base + p] = s;
  }
  if (b == 0 && t == 0) offs[N_NODES] = TOTE;
}

// ====================== GEMM [M,128] @ [128,128] (fp32 vector ALU, bf16 out) ======================
__global__ __launch_bounds__(256) void k_gemm(const float* __restrict__ A, const float* __restrict__ W,
                                              unsigned short* __restrict__ Cb) {
  __shared__ float sA[128][36];
  __shared__ float sB[32][128];
  int t = threadIdx.x;
  int row0 = blockIdx.x * 128;
  int tx = t & 15;
  int ty = t >> 4;
  float acc[8][8];
#pragma unroll
  for (int i = 0; i < 8; ++i)
#pragma unroll
    for (int j = 0; j < 8; ++j) acc[i][j] = 0.f;

  for (int k0 = 0; k0 < 128; k0 += 32) {
#pragma unroll
    for (int i = 0; i < 4; ++i) {
      int f = t + i * 256;
      int r = f >> 3, c4 = f & 7;
      float4 v = make_float4(0.f, 0.f, 0.f, 0.f);
      int gr = row0 + r;
      if (gr < N_NODES) v = *reinterpret_cast<const float4*>(A + (size_t)gr * 128 + k0 + c4 * 4);
      *reinterpret_cast<float4*>(&sA[r][c4 * 4]) = v;
    }
#pragma unroll
    for (int i = 0; i < 4; ++i) {
      int f = t + i * 256;
      int r = f >> 5, c4 = f & 31;
      *reinterpret_cast<float4*>(&sB[r][c4 * 4]) =
          *reinterpret_cast<const float4*>(W + (size_t)(k0 + r) * 128 + c4 * 4);
    }
    __syncthreads();
#pragma unroll
    for (int k = 0; k < 32; ++k) {
      float a[8], bb[8];
#pragma unroll
      for (int i = 0; i < 8; ++i) a[i] = sA[ty * 8 + i][k];
      float4 b0 = *reinterpret_cast<const float4*>(&sB[k][tx * 8]);
      float4 b1 = *reinterpret_cast<const float4*>(&sB[k][tx * 8 + 4]);
      bb[0] = b0.x; bb[1] = b0.y; bb[2] = b0.z; bb[3] = b0.w;
      bb[4] = b1.x; bb[5] = b1.y; bb[6] = b1.z; bb[7] = b1.w;
#pragma unroll
      for (int i = 0; i < 8; ++i)
#pragma unroll
        for (int j = 0; j < 8; ++j) acc[i][j] += a[i] * bb[j];
    }
    __syncthreads();
  }
#pragma unroll
  for (int i = 0; i < 8; ++i) {
    int gr = row0 + ty * 8 + i;
    if (gr < N_NODES) {
      union { unsigned short us[8]; uint4 u4; } o;
#pragma unroll
      for (int j = 0; j < 8; ++j) o.us[j] = f2bf(acc[i][j]);
      *reinterpret_cast<uint4*>(Cb + (size_t)gr * 128 + tx * 8) = o.u4;
    }
  }
}

// ====================== per-node attention scalars (bf16 h) ======================
__global__ __launch_bounds__(256) void k_alphas(const unsigned short* __restrict__ hb,
                                                const float* __restrict__ avS,
                                                const float* __restrict__ avD,
                                                float* __restrict__ outS, float* __restrict__ outD) {
  int gw = (blockIdx.x * 256 + threadIdx.x) >> 6;
  int lane = threadIdx.x & 63;
  if (gw >= N_NODES) return;
  unsigned int r = *reinterpret_cast<const unsigned int*>(hb + (size_t)gw * 128 + lane * 2);
  float hx = bf_lo(r), hy = bf_hi(r);
  float2 sv = *reinterpret_cast<const float2*>(avS + lane * 2);
  float2 dv = *reinterpret_cast<const float2*>(avD + lane * 2);
  float ps = hx * sv.x + hy * sv.y;
  float pd = hx * dv.x + hy * dv.y;
#pragma unroll
  for (int off = 32; off > 0; off >>= 1) {
    ps += __shfl_xor(ps, off);
    pd += __shfl_xor(pd, off);
  }
  if (lane == 0) { outS[gw] = ps; outD[gw] = pd; }
}

// ====================== softmax + weighted aggregation (wave per dst node, bf16 gather) ==========
__global__ __launch_bounds__(256) void k_aggregate(const unsigned short* __restrict__ hb,
                                                   const float* __restrict__ aS,
                                                   const float* __restrict__ aD, const int* __restrict__ offs,
                                                   const int* __restrict__ srcs, const float* __restrict__ bias,
                                                   float* __restrict__ out, int relu) {
  int gw = (blockIdx.x * 256 + threadIdx.x) >> 6;
  int lane = threadIdx.x & 63;
  if (gw >= N_NODES) return;
  int beg = offs[gw], end = offs[gw + 1];
  float adn = aD[gw];

  float m = -1e30f;
  for (int i = beg + lane; i < end; i += 64) {
    float e = aS[srcs[i]] + adn;
    e = (e > 0.f) ? e : NEG * e;
    m = fmaxf(m, e);
  }
#pragma unroll
  for (int off = 32; off > 0; off >>= 1) m = fmaxf(m, __shfl_xor(m, off));

  float denom = 0.f, acc0 = 0.f, acc1 = 0.f;
  const unsigned int laneOff = lane * 2;
  for (int base = beg; base < end; base += 64) {
    int i = base + lane;
    float ex = 0.f; int s = 0;
    if (i < end) {
      s = srcs[i];
      float e = aS[s] + adn;
      e = (e > 0.f) ? e : NEG * e;
      ex = __expf(e - m);
    }
    denom += ex;
    int cnt = min(64, end - base);
    int j = 0;
    for (; j + 8 <= cnt; j += 8) {
      float e0 = __shfl(ex, j + 0), e1 = __shfl(ex, j + 1), e2 = __shfl(ex, j + 2), e3 = __shfl(ex, j + 3);
      float e4 = __shfl(ex, j + 4), e5 = __shfl(ex, j + 5), e6 = __shfl(ex, j + 6), e7 = __shfl(ex, j + 7);
      int s0 = __shfl(s, j + 0), s1 = __shfl(s, j + 1), s2 = __shfl(s, j + 2), s3 = __shfl(s, j + 3);
      int s4 = __shfl(s, j + 4), s5 = __shfl(s, j + 5), s6 = __shfl(s, j + 6), s7 = __shfl(s, j + 7);
      unsigned int r0 = *reinterpret_cast<const unsigned int*>(hb + (size_t)s0 * 128 + laneOff);
      unsigned int r1 = *reinterpret_cast<const unsigned int*>(hb + (size_t)s1 * 128 + laneOff);
      unsigned int r2 = *reinterpret_cast<const unsigned int*>(hb + (size_t)s2 * 128 + laneOff);
      unsigned int r3 = *reinterpret_cast<const unsigned int*>(hb + (size_t)s3 * 128 + laneOff);
      unsigned int r4 = *reinterpret_cast<const unsigned int*>(hb + (size_t)s4 * 128 + laneOff);
      unsigned int r5 = *reinterpret_cast<const unsigned int*>(hb + (size_t)s5 * 128 + laneOff);
      unsigned int r6 = *reinterpret_cast<const unsigned int*>(hb + (size_t)s6 * 128 + laneOff);
      unsigned int r7 = *reinterpret_cast<const unsigned int*>(hb + (size_t)s7 * 128 + laneOff);
      acc0 += e0 * bf_lo(r0); acc1 += e0 * bf_hi(r0);
      acc0 += e1 * bf_lo(r1); acc1 += e1 * bf_hi(r1);
      acc0 += e2 * bf_lo(r2); acc1 += e2 * bf_hi(r2);
      acc0 += e3 * bf_lo(r3); acc1 += e3 * bf_hi(r3);
      acc0 += e4 * bf_lo(r4); acc1 += e4 * bf_hi(r4);
      acc0 += e5 * bf_lo(r5); acc1 += e5 * bf_hi(r5);
      acc0 += e6 * bf_lo(r6); acc1 += e6 * bf_hi(r6);
      acc0 += e7 * bf_lo(r7); acc1 += e7 * bf_hi(r7);
    }
    for (; j < cnt; ++j) {
      float exj = __shfl(ex, j);
      int sj = __shfl(s, j);
      unsigned int r = *reinterpret_cast<const unsigned int*>(hb + (size_t)sj * 128 + laneOff);
      acc0 += exj * bf_lo(r);
      acc1 += exj * bf_hi(r);
    }
  }
#pragma unroll
  for (int off = 32; off > 0; off >>= 1) denom += __shfl_xor(denom, off);
  float inv = 1.f / (denom + 1e-16f);
  float2 bv = *reinterpret_cast<const float2*>(bias + lane * 2);
  float o0 = acc0 * inv + bv.x;
  float o1 = acc1 * inv + bv.y;
  if (relu) { o0 = fmaxf(o0, 0.f); o1 = fmaxf(o1, 0.f); }
  *reinterpret_cast<float2*>(out + (size_t)gw * 128 + lane * 2) = make_float2(o0, o1);
}

// ====================== final classifier [N,128]@[128,10]+b ======================
__global__ __launch_bounds__(256) void k_linear(const float* __restrict__ h, const float* __restrict__ Wl,
                                                const float* __restrict__ bl, float* __restrict__ out) {
  __shared__ float sW[128 * 10];
  __shared__ float sb[10];
  int t = threadIdx.x;
  for (int i = t; i < 1280; i += 256) sW[i] = Wl[i];
  if (t < 10) sb[t] = bl[t];
  __syncthreads();
  int gw = (blockIdx.x * 256 + t) >> 6;
  int lane = t & 63;
  if (gw >= N_NODES) return;
  float2 hv = *reinterpret_cast<const float2*>(h + (size_t)gw * 128 + lane * 2);
  float p[10];
#pragma unroll
  for (int c = 0; c < 10; ++c)
    p[c] = hv.x * sW[(2 * lane) * 10 + c] + hv.y * sW[(2 * lane + 1) * 10 + c];
#pragma unroll
  for (int off = 32; off > 0; off >>= 1)
#pragma unroll
    for (int c = 0; c < 10; ++c) p[c] += __shfl_xor(p[c], off);
  if (lane == 0) {
#pragma unroll
    for (int c = 0; c < 10; ++c) out[(size_t)gw * 10 + c] = p[c] + sb[c];
  }
}

// ====================== launch ======================
extern "C" void kernel_launch(void* const* d_in, const int* in_sizes, int n_in,
                              void* d_out, int out_size, void* d_ws, size_t ws_size,
                              hipStream_t stream) {
  const float* x   = (const float*)d_in[0];
  const int*   ei  = (const int*)d_in[1];
  const float* W1  = (const float*)d_in[3];
  const float* as1 = (const float*)d_in[4];
  const float* ad1 = (const float*)d_in[5];
  const float* b1  = (const float*)d_in[6];
  const float* W2  = (const float*)d_in[7];
  const float* as2 = (const float*)d_in[8];
  const float* ad2 = (const float*)d_in[9];
  const float* b2  = (const float*)d_in[10];
  const float* Wl  = (const float*)d_in[11];
  const float* bl  = (const float*)d_in[12];
  float* out = (float*)d_out;

  char* p = (char*)d_ws;
  unsigned short* hb = (unsigned short*)p; p += (size_t)N_NODES * 128 * sizeof(unsigned short);
  float* bufB  = (float*)p; p += (size_t)N_NODES * 128 * sizeof(float);
  float* aS    = (float*)p; p += (size_t)N_NODES * sizeof(float);
  float* aD    = (float*)p; p += (size_t)N_NODES * sizeof(float);
  int* offs    = (int*)p;   p += (size_t)(N_NODES + 4) * sizeof(int);
  int* srcs    = (int*)p;   p += (size_t)TOTE * sizeof(int);
  int* bucketCnt = (int*)p; p += (size_t)NB * 16 * sizeof(int);
  int* binOffs   = (int*)p; p += (size_t)(NB + 4) * sizeof(int);
  int* binCursor = (int*)p; p += (size_t)NB * 16 * sizeof(int);
  // binned pair array aliases bufB (only live during CSR build, before any aggregate)
  unsigned int* binned = (unsigned int*)bufB;

  int binBlocks = (N_EDGES + 4095) / 4096;  // 391

  k_zero_bcnt<<<1, 256, 0, stream>>>(bucketCnt);
  k_bucket_hist<<<binBlocks, 256, 0, stream>>>(ei, bucketCnt);
  k_bin_scan<<<1, 512, 0, stream>>>(bucketCnt, binOffs, binCursor);
  k_binA<<<binBlocks, 256, 0, stream>>>(ei, binCursor, binned);
  k_binB<<<NB, 256, 0, stream>>>(binned, binOffs, offs, srcs);

  int gemmBlocks = (N_NODES + 127) / 128;
  int waveBlocks = (N_NODES + 3) / 4;

  // layer 1
  k_gemm<<<gemmBlocks, 256, 0, stream>>>(x, W1, hb);
  k_alphas<<<waveBlocks, 256, 0, stream>>>(hb, as1, ad1, aS, aD);
  k_aggregate<<<waveBlocks, 256, 0, stream>>>(hb, aS, aD, offs, srcs, b1, bufB, 1);
  // layer 2
  k_gemm<<<gemmBlocks, 256, 0, stream>>>(bufB, W2, hb);
  k_alphas<<<waveBlocks, 256, 0, stream>>>(hb, as2, ad2, aS, aD);
  k_aggregate<<<waveBlocks, 256, 0, stream>>>(hb, aS, aD, offs, srcs, b2, bufB, 1);
  // classifier
  k_linear<<<waveBlocks, 256, 0, stream>>>(bufB, Wl, bl, out);
}